// Round 8
// baseline (2273.236 us; speedup 1.0000x reference)
//
#include <hip/hip_runtime.h>
#include <cmath>

#define D_MODEL 256
#define NHEADS 8
#define BSZ 8
#define S_TOT 4725
#define NQRY 3600

typedef unsigned short ushortT;
using bf16x8  = __attribute__((ext_vector_type(8))) __bf16;
using floatx4 = __attribute__((ext_vector_type(4))) float;

__device__ __forceinline__ ushortT f2bf(float f)
{
    union { float f; unsigned u; } v; v.f = f;
    unsigned r = v.u + 0x7FFFu + ((v.u >> 16) & 1u);
    return (ushortT)(r >> 16);
}
__device__ __forceinline__ float bf2f(ushortT u)
{
    union { unsigned u; float f; } v; v.u = ((unsigned)u) << 16;
    return v.f;
}
__device__ __forceinline__ float bits2f(unsigned u)
{
    union { unsigned u; float f; } v; v.u = u;
    return v.f;
}

#define GLD16(gp, lp) __builtin_amdgcn_global_load_lds( \
    (const __attribute__((address_space(1))) void*)(gp), \
    (__attribute__((address_space(3))) void*)(lp), 16, 0, 0)

// ---------------------------------------------------------------------------
// bf16 MFMA GEMM with async global->LDS staging. (unchanged from round 7)
// ---------------------------------------------------------------------------
template<int RELU, int OUTBF>
__global__ __launch_bounds__(256) void gemm_bf16_kernel(
    const ushortT* __restrict__ A, const ushortT* __restrict__ W,
    const float* __restrict__ bias, void* __restrict__ Cout,
    int M, int N, int K)
{
    __shared__ ushortT SM[128 * 32 * 2];
    ushortT* As = SM;
    ushortT* Bs = SM + 128 * 32;
    const int tid  = threadIdx.x;
    const int lane = tid & 63;
    const int wid  = tid >> 6;
    const int bm = blockIdx.x * 128;
    const int bn = blockIdx.y * 128;
    const int wm = (wid & 1) * 64;
    const int wn = (wid >> 1) * 64;
    const int col16 = lane & 15;
    const int quad  = lane >> 4;
    const int srow = lane >> 2;
    const int cperm = (lane & 3) ^ ((lane >> 3) & 3);
    const int rxor = (col16 >> 1) & 3;

    floatx4 acc[4][4];
#pragma unroll
    for (int i = 0; i < 4; i++)
#pragma unroll
        for (int j = 0; j < 4; j++) acc[i][j] = (floatx4){0.f, 0.f, 0.f, 0.f};

    const int rbase = wid * 32;
    for (int k0 = 0; k0 < K; k0 += 32) {
        if (k0) __syncthreads();
#pragma unroll
        for (int j = 0; j < 2; j++) {
            int row = rbase + j * 16 + srow;
            int gm = bm + row; if (gm >= M) gm = M - 1;
            GLD16(A + (size_t)gm * K + k0 + cperm * 8, &As[(rbase + j * 16) * 32]);
            int gn = bn + row; if (gn >= N) gn = N - 1;
            GLD16(W + (size_t)gn * K + k0 + cperm * 8, &Bs[(rbase + j * 16) * 32]);
        }
        __syncthreads();
        bf16x8 av[4], bv[4];
#pragma unroll
        for (int i = 0; i < 4; i++) {
            av[i] = *(const bf16x8*)&As[(wm + i * 16 + col16) * 32 + (quad ^ rxor) * 8];
            bv[i] = *(const bf16x8*)&Bs[(wn + i * 16 + col16) * 32 + (quad ^ rxor) * 8];
        }
#pragma unroll
        for (int mi = 0; mi < 4; mi++)
#pragma unroll
            for (int ni = 0; ni < 4; ni++)
                acc[mi][ni] = __builtin_amdgcn_mfma_f32_16x16x32_bf16(
                    av[mi], bv[ni], acc[mi][ni], 0, 0, 0);
    }

    if (OUTBF) {
        __syncthreads();
        ushortT* cs = SM + wid * (16 * 72);
        const int row_l = lane >> 2;
        const int colg  = (lane & 3) * 16;
#pragma unroll
        for (int mi = 0; mi < 4; mi++) {
#pragma unroll
            for (int ni = 0; ni < 4; ni++) {
                int gn = bn + wn + ni * 16 + col16;
                float bs = bias[gn < N ? gn : N - 1];
#pragma unroll
                for (int r = 0; r < 4; r++) {
                    float v = acc[mi][ni][r] + bs;
                    if (RELU) v = fmaxf(v, 0.f);
                    cs[(quad * 4 + r) * 72 + ni * 16 + col16] = f2bf(v);
                }
            }
            int gm = bm + wm + mi * 16 + row_l;
            int gn0 = bn + wn + colg;
            if (gm < M) {
                ushortT* dst = (ushortT*)Cout + (size_t)gm * N + gn0;
                if (gn0 + 8 <= N)  *(uint4*)dst       = *(uint4*)&cs[row_l * 72 + colg];
                if (gn0 + 16 <= N) *(uint4*)(dst + 8) = *(uint4*)&cs[row_l * 72 + colg + 8];
            }
        }
    } else {
#pragma unroll
        for (int ni = 0; ni < 4; ni++) {
            int gn = bn + wn + ni * 16 + col16;
            if (gn >= N) continue;
            float bs = bias[gn];
#pragma unroll
            for (int mi = 0; mi < 4; mi++) {
#pragma unroll
                for (int r = 0; r < 4; r++) {
                    int gm = bm + wm + mi * 16 + quad * 4 + r;
                    if (gm >= M) continue;
                    float v = acc[mi][ni][r] + bs;
                    if (RELU) v = fmaxf(v, 0.f);
                    ((float*)Cout)[(size_t)gm * N + gn] = v;
                }
            }
        }
    }
}

static inline void gemm_bf16(const ushortT* A, const ushortT* W, const float* bias,
                             void* C, int M, int N, int K, int relu, int outbf,
                             hipStream_t s)
{
    dim3 g((M + 127) / 128, (N + 127) / 128);
    if (relu) {
        if (outbf) hipLaunchKernelGGL((gemm_bf16_kernel<1,1>), g, dim3(256), 0, s, A, W, bias, C, M, N, K);
        else       hipLaunchKernelGGL((gemm_bf16_kernel<1,0>), g, dim3(256), 0, s, A, W, bias, C, M, N, K);
    } else {
        if (outbf) hipLaunchKernelGGL((gemm_bf16_kernel<0,1>), g, dim3(256), 0, s, A, W, bias, C, M, N, K);
        else       hipLaunchKernelGGL((gemm_bf16_kernel<0,0>), g, dim3(256), 0, s, A, W, bias, C, M, N, K);
    }
}

// ---------------------------------------------------------------------------
__global__ void f2bf_kernel(const float* __restrict__ src, ushortT* __restrict__ dst, int n)
{
    int t = blockIdx.x * blockDim.x + threadIdx.x;
    if (t < n) dst[t] = f2bf(src[t]);
}

__global__ void conv_offaw_kernel(const float* __restrict__ offW, const float* __restrict__ awW,
                                  ushortT* __restrict__ dst)
{
    int t = blockIdx.x * blockDim.x + threadIdx.x;
    if (t >= 3 * 288 * 256) return;
    int c = t & 255;
    int r = (t >> 8) % 288;
    int i = t / (288 * 256);
    float v = (r < 192) ? offW[((size_t)i * 192 + r) * 256 + c]
                        : awW[((size_t)i * 96 + (r - 192)) * 256 + c];
    dst[t] = f2bf(v);
}

__global__ void conv_offaw_bias_kernel(const float* __restrict__ offb, const float* __restrict__ awb,
                                       float* __restrict__ dst)
{
    int t = blockIdx.x * blockDim.x + threadIdx.x;
    if (t >= 3 * 288) return;
    int r = t % 288;
    int i = t / 288;
    dst[t] = (r < 192) ? offb[i * 192 + r] : awb[i * 96 + (r - 192)];
}

__device__ __forceinline__ void level_of(int s, int& l, int& H, int& W, int& hw)
{
    if (s < 3600)      { l = 0; H = 60; W = 60; hw = s; }
    else if (s < 4500) { l = 1; H = 30; W = 30; hw = s - 3600; }
    else               { l = 2; H = 15; W = 15; hw = s - 4500; }
}

__global__ __launch_bounds__(256) void transpose_feat_kernel(
    const float* __restrict__ f, ushortT* __restrict__ Xh, int HW, int s0)
{
    __shared__ float tile[32][33];
    const int b  = blockIdx.z;
    const int hw0 = blockIdx.x * 32;
    const int d0  = blockIdx.y * 32;
    const int tx = threadIdx.x & 31;
    const int ty = threadIdx.x >> 5;
    const float* fb = f + ((size_t)b * 256 + d0) * HW + hw0;
#pragma unroll
    for (int r = ty; r < 32; r += 8) {
        if (hw0 + tx < HW) tile[r][tx] = fb[(size_t)r * HW + tx];
    }
    __syncthreads();
    ushortT* xb = Xh + ((size_t)b * S_TOT + s0 + hw0) * 256 + d0;
#pragma unroll
    for (int r = ty; r < 32; r += 8) {
        if (hw0 + r < HW) xb[(size_t)r * 256 + tx] = f2bf(tile[tx][r]);
    }
}

__global__ void build_pos_kernel(const float* __restrict__ level_embed, float* __restrict__ pos)
{
    int t = blockIdx.x * blockDim.x + threadIdx.x;
    if (t >= S_TOT * D_MODEL) return;
    int d = t & 255;
    int s = t >> 8;
    int l, H, W, hw; level_of(s, l, H, W, hw);
    int y = hw / W, x = hw % W;
    int dd = (d < 128) ? d : d - 128;
    float v = (d < 128)
        ? ((float)(y + 1)) / ((float)H + 1e-6f) * 6.28318530717958647692f
        : ((float)(x + 1)) / ((float)W + 1e-6f) * 6.28318530717958647692f;
    float tpow = powf(10000.f, (float)(2 * (dd >> 1)) * (1.f / 128.f));
    float arg = v / tpow;
    float val = (dd & 1) ? cosf(arg) : sinf(arg);
    pos[t] = val + level_embed[l * D_MODEL + d];
}

__global__ void build_ref_kernel(float* __restrict__ refE, float* __restrict__ refD)
{
    int t = blockIdx.x * blockDim.x + threadIdx.x;
    if (t < S_TOT) {
        int l, H, W, hw; level_of(t, l, H, W, hw);
        int y = hw / W, x = hw % W;
        refE[2 * t]     = ((float)x + 0.5f) / (float)W;
        refE[2 * t + 1] = ((float)y + 0.5f) / (float)H;
    } else if (t < S_TOT + NQRY) {
        int q = t - S_TOT;
        int y = q / 60, x = q % 60;
        refD[2 * q]     = ((float)x + 0.5f) / 60.f;
        refD[2 * q + 1] = ((float)y + 0.5f) / 60.f;
    }
}

__global__ void build_tgt_kernel(const float* __restrict__ context, const float* __restrict__ qe,
                                 ushortT* __restrict__ TGTh)
{
    int t = blockIdx.x * blockDim.x + threadIdx.x;
    if (t >= NQRY * BSZ * 64) return;
    int gi = t & 63;
    int row = t >> 6;
    int nq = row >> 3;
    int d0 = gi * 4;
    const float4 c4 = *(const float4*)(context + (size_t)row * 256 + d0);
    const float4 q4 = *(const float4*)(qe + (size_t)nq * 256 + d0);
    ushortT pk[4] = { f2bf(c4.x + q4.x), f2bf(c4.y + q4.y), f2bf(c4.z + q4.z), f2bf(c4.w + q4.w) };
    *(uint2*)(TGTh + (size_t)row * 256 + d0) = *(uint2*)pk;
}

__global__ void add_pos_kernel(const ushortT* __restrict__ Xh, const float* __restrict__ pos,
                               ushortT* __restrict__ Qh)
{
    int t = blockIdx.x * blockDim.x + threadIdx.x;
    if (t >= BSZ * S_TOT * 64) return;
    int gi = t & 63;
    int row = t >> 6;
    int s = row % S_TOT;
    int d0 = gi * 4;
    ushortT x4[4];
    *(uint2*)x4 = *(const uint2*)(Xh + (size_t)row * 256 + d0);
    const float4 p4 = *(const float4*)(pos + (size_t)s * 256 + d0);
    ushortT pk[4] = { f2bf(bf2f(x4[0]) + p4.x), f2bf(bf2f(x4[1]) + p4.y),
                      f2bf(bf2f(x4[2]) + p4.z), f2bf(bf2f(x4[3]) + p4.w) };
    *(uint2*)(Qh + (size_t)row * 256 + d0) = *(uint2*)pk;
}

// ---------------------------------------------------------------------------
// MSDA sampling, branchless gathers: block = 8 rows; thread = (row, head, cg).
// Corner loads are unconditional (clamped indices); out-of-range handled by
// zeroed corner weights — identical to zero-padding. All 4 corner loads of a
// tap are issued before any dependent FMA so the compiler can batch them.
// ---------------------------------------------------------------------------
#define MROWS 8
__global__ __launch_bounds__(256) void msda_kernel(
    const ushortT* __restrict__ value, const float* __restrict__ oa,
    const float* __restrict__ ref, ushortT* __restrict__ out,
    int mode, int total_rows)
{
    __shared__ float sOff[MROWS][192];
    __shared__ float sW[MROWS][96];
    const int br0 = blockIdx.x * MROWS;

    for (int idx = threadIdx.x; idx < MROWS * 288; idx += 256) {
        int r = idx / 288, c = idx - r * 288;
        int lm = br0 + r;
        float v = (lm < total_rows) ? oa[(size_t)lm * 288 + c] : 0.f;
        if (c < 192) sOff[r][c] = v;
        else         sW[r][c - 192] = v;
    }
    __syncthreads();
    if (threadIdx.x < 64) {
        int r = threadIdx.x >> 3, h = threadIdx.x & 7;
        float* p = &sW[r][h * 12];
        float mx = p[0];
#pragma unroll
        for (int i = 1; i < 12; i++) mx = fmaxf(mx, p[i]);
        float ssum = 0.f;
        float e[12];
#pragma unroll
        for (int i = 0; i < 12; i++) { e[i] = expf(p[i] - mx); ssum += e[i]; }
        float inv = 1.f / ssum;
#pragma unroll
        for (int i = 0; i < 12; i++) p[i] = e[i] * inv;
    }
    __syncthreads();

    const int r  = threadIdx.x >> 5;
    const int h  = (threadIdx.x >> 2) & 7;
    const int cg = threadIdx.x & 3;
    const int lm = br0 + r;
    if (lm >= total_rows) return;
    int b, q;
    if (mode == 0) { b = lm / S_TOT; q = lm - b * S_TOT; }
    else           { q = lm >> 3;    b = lm & 7; }
    const float rx = ref[2 * q], ry = ref[2 * q + 1];
    const float* offp = &sOff[r][h * 24];
    const float* wp   = &sW[r][h * 12];

    float acc[8] = {};
    const int HWs[3][3] = {{60, 60, 0}, {30, 30, 3600}, {15, 15, 4500}};
#pragma unroll
    for (int l = 0; l < 3; l++) {
        const int H = HWs[l][0], W = HWs[l][1], s0 = HWs[l][2];
        const ushortT* vbase = value + ((size_t)b * S_TOT + s0) * 256 + h * 32 + cg * 8;
#pragma unroll
        for (int p = 0; p < 4; p++) {
            float ox = offp[(l * 4 + p) * 2];
            float oy = offp[(l * 4 + p) * 2 + 1];
            float w  = wp[l * 4 + p];
            float lx = rx * W + ox - 0.5f;
            float ly = ry * H + oy - 0.5f;
            float x0f = floorf(lx), y0f = floorf(ly);
            int x0 = (int)x0f, y0 = (int)y0f;
            float wx1 = lx - x0f, wy1 = ly - y0f;
            // masked axis weights (zero outside -> zero padding semantics)
            float mx0 = ((unsigned)x0       < (unsigned)W) ? (1.f - wx1) : 0.f;
            float mx1 = ((unsigned)(x0 + 1) < (unsigned)W) ? wx1         : 0.f;
            float my0 = ((unsigned)y0       < (unsigned)H) ? (1.f - wy1) : 0.f;
            float my1 = ((unsigned)(y0 + 1) < (unsigned)H) ? wy1         : 0.f;
            // clamped indices (always in-range -> unconditional loads)
            int xc0 = min(max(x0, 0), W - 1);
            int xc1 = min(max(x0 + 1, 0), W - 1);
            int yc0 = min(max(y0, 0), H - 1);
            int yc1 = min(max(y0 + 1, 0), H - 1);
            const uint4 v00 = *(const uint4*)(vbase + (size_t)(yc0 * W + xc0) * 256);
            const uint4 v01 = *(const uint4*)(vbase + (size_t)(yc0 * W + xc1) * 256);
            const uint4 v10 = *(const uint4*)(vbase + (size_t)(yc1 * W + xc0) * 256);
            const uint4 v11 = *(const uint4*)(vbase + (size_t)(yc1 * W + xc1) * 256);
            float w00 = w * my0 * mx0, w01 = w * my0 * mx1;
            float w10 = w * my1 * mx0, w11 = w * my1 * mx1;
#define ACC4(i, lo00, lo01, lo10, lo11) \
            acc[i] = fmaf(w00, bits2f(lo00), acc[i]); \
            acc[i] = fmaf(w01, bits2f(lo01), acc[i]); \
            acc[i] = fmaf(w10, bits2f(lo10), acc[i]); \
            acc[i] = fmaf(w11, bits2f(lo11), acc[i]);
            ACC4(0, v00.x << 16, v01.x << 16, v10.x << 16, v11.x << 16)
            ACC4(1, v00.x & 0xFFFF0000u, v01.x & 0xFFFF0000u, v10.x & 0xFFFF0000u, v11.x & 0xFFFF0000u)
            ACC4(2, v00.y << 16, v01.y << 16, v10.y << 16, v11.y << 16)
            ACC4(3, v00.y & 0xFFFF0000u, v01.y & 0xFFFF0000u, v10.y & 0xFFFF0000u, v11.y & 0xFFFF0000u)
            ACC4(4, v00.z << 16, v01.z << 16, v10.z << 16, v11.z << 16)
            ACC4(5, v00.z & 0xFFFF0000u, v01.z & 0xFFFF0000u, v10.z & 0xFFFF0000u, v11.z & 0xFFFF0000u)
            ACC4(6, v00.w << 16, v01.w << 16, v10.w << 16, v11.w << 16)
            ACC4(7, v00.w & 0xFFFF0000u, v01.w & 0xFFFF0000u, v10.w & 0xFFFF0000u, v11.w & 0xFFFF0000u)
#undef ACC4
        }
    }
    ushortT pk[8];
#pragma unroll
    for (int i = 0; i < 8; i++) pk[i] = f2bf(acc[i]);
    *(uint4*)(out + (size_t)lm * 256 + h * 32 + cg * 8) = *(uint4*)pk;
}

// ---------------------------------------------------------------------------
// LN over bf16 residual stream
// ---------------------------------------------------------------------------
__global__ void ln_res_kernel(const ushortT* __restrict__ x, const ushortT* __restrict__ a,
                              const float* __restrict__ g, const float* __restrict__ b,
                              ushortT* __restrict__ outh, float* __restrict__ outf, int M)
{
    int wave = threadIdx.x >> 6;
    int lane = threadIdx.x & 63;
    int row = blockIdx.x * 4 + wave;
    if (row >= M) return;
    const int d0 = lane * 4;
    ushortT x4[4], a4[4];
    *(uint2*)x4 = *(const uint2*)(x + (size_t)row * 256 + d0);
    *(uint2*)a4 = *(const uint2*)(a + (size_t)row * 256 + d0);
    float v[4];
    float s = 0.f;
#pragma unroll
    for (int i = 0; i < 4; i++) { v[i] = bf2f(x4[i]) + bf2f(a4[i]); s += v[i]; }
#pragma unroll
    for (int o = 32; o > 0; o >>= 1) s += __shfl_down(s, o);
    s = __shfl(s, 0);
    float mean = s * (1.f / 256.f);
    float vs = 0.f;
#pragma unroll
    for (int i = 0; i < 4; i++) { float d = v[i] - mean; vs += d * d; }
#pragma unroll
    for (int o = 32; o > 0; o >>= 1) vs += __shfl_down(vs, o);
    vs = __shfl(vs, 0);
    float inv = rsqrtf(vs * (1.f / 256.f) + 1e-5f);
    const float4 g4 = *(const float4*)(g + d0);
    const float4 b4 = *(const float4*)(b + d0);
    float o0 = (v[0] - mean) * inv * g4.x + b4.x;
    float o1 = (v[1] - mean) * inv * g4.y + b4.y;
    float o2 = (v[2] - mean) * inv * g4.z + b4.z;
    float o3 = (v[3] - mean) * inv * g4.w + b4.w;
    ushortT pk[4] = { f2bf(o0), f2bf(o1), f2bf(o2), f2bf(o3) };
    *(uint2*)(outh + (size_t)row * 256 + d0) = *(uint2*)pk;
    if (outf) {
        float4 of = { o0, o1, o2, o3 };
        *(float4*)(outf + (size_t)row * 256 + d0) = of;
    }
}

// Decoder self-attn over L=8 (batch). qkv bf16 rows n*8+l; out bf16.
__global__ void mha_kernel(const ushortT* __restrict__ qkv, ushortT* __restrict__ o, int nCnt)
{
    int t = blockIdx.x * blockDim.x + threadIdx.x;
    if (t >= nCnt * 64) return;
    int l = t & 7;
    int h = (t >> 3) & 7;
    int n = t >> 6;
    const ushortT* qp = qkv + (size_t)(n * 8 + l) * 768 + h * 32;
    float q[32];
#pragma unroll
    for (int d = 0; d < 32; d++) q[d] = bf2f(qp[d]);
    float sc[8];
#pragma unroll
    for (int s = 0; s < 8; s++) {
        const ushortT* kp = qkv + (size_t)(n * 8 + s) * 768 + 256 + h * 32;
        float acc = 0.f;
#pragma unroll
        for (int d = 0; d < 32; d++) acc = fmaf(q[d], bf2f(kp[d]), acc);
        sc[s] = acc * 0.17677669529663688f;
    }
    float mx = sc[0];
#pragma unroll
    for (int s = 1; s < 8; s++) mx = fmaxf(mx, sc[s]);
    float sum = 0.f;
#pragma unroll
    for (int s = 0; s < 8; s++) { sc[s] = expf(sc[s] - mx); sum += sc[s]; }
    float inv = 1.f / sum;
    float outv[32] = {};
#pragma unroll
    for (int s = 0; s < 8; s++) {
        const ushortT* vp = qkv + (size_t)(n * 8 + s) * 768 + 512 + h * 32;
        float a = sc[s] * inv;
#pragma unroll
        for (int d = 0; d < 32; d++) outv[d] = fmaf(a, bf2f(vp[d]), outv[d]);
    }
    ushortT* op = o + (size_t)(n * 8 + l) * 256 + h * 32;
#pragma unroll
    for (int d = 0; d < 32; d++) op[d] = f2bf(outv[d]);
}

// ---------------------------------------------------------------------------
extern "C" void kernel_launch(void* const* d_in, const int* in_sizes, int n_in,
                              void* d_out, int out_size, void* d_ws, size_t ws_size,
                              hipStream_t stream)
{
    const float* feat0       = (const float*)d_in[0];
    const float* feat1       = (const float*)d_in[1];
    const float* feat2       = (const float*)d_in[2];
    const float* context     = (const float*)d_in[3];
    const float* query_embed = (const float*)d_in[4];
    const float* level_embed = (const float*)d_in[5];
    const float* enc_off_W = (const float*)d_in[6];
    const float* enc_off_b = (const float*)d_in[7];
    const float* enc_aw_W  = (const float*)d_in[8];
    const float* enc_aw_b  = (const float*)d_in[9];
    const float* enc_vp_W  = (const float*)d_in[10];
    const float* enc_vp_b  = (const float*)d_in[11];
    const float* enc_op_W  = (const float*)d_in[12];
    const float* enc_op_b  = (const float*)d_in[13];
    const float* enc_fc1_W = (const float*)d_in[14];
    const float* enc_fc1_b = (const float*)d_in[15];
    const float* enc_fc2_W = (const float*)d_in[16];
    const float* enc_fc2_b = (const float*)d_in[17];
    const float* enc_ln1_g = (const float*)d_in[18];
    const float* enc_ln1_b = (const float*)d_in[19];
    const float* enc_ln2_g = (const float*)d_in[20];
    const float* enc_ln2_b = (const float*)d_in[21];
    const float* dec_off_W = (const float*)d_in[22];
    const float* dec_off_b = (const float*)d_in[23];
    const float* dec_aw_W  = (const float*)d_in[24];
    const float* dec_aw_b  = (const float*)d_in[25];
    const float* dec_vp_W  = (const float*)d_in[26];
    const float* dec_vp_b  = (const float*)d_in[27];
    const float* dec_op_W  = (const float*)d_in[28];
    const float* dec_op_b  = (const float*)d_in[29];
    const float* dec_fc1_W = (const float*)d_in[30];
    const float* dec_fc1_b = (const float*)d_in[31];
    const float* dec_fc2_W = (const float*)d_in[32];
    const float* dec_fc2_b = (const float*)d_in[33];
    const float* dec_ln1_g = (const float*)d_in[34];
    const float* dec_ln1_b = (const float*)d_in[35];
    const float* dec_ln2_g = (const float*)d_in[36];
    const float* dec_ln2_b = (const float*)d_in[37];
    const float* sa_in_W   = (const float*)d_in[38];
    const float* sa_in_b   = (const float*)d_in[39];
    const float* sa_out_W  = (const float*)d_in[40];
    const float* sa_out_b  = (const float*)d_in[41];
    const float* dec_ln3_g = (const float*)d_in[42];
    const float* dec_ln3_b = (const float*)d_in[43];

    const int ME = BSZ * S_TOT;       // 37800
    const int MD = BSZ * NQRY;        // 28800
    const int EW = ME * D_MODEL;
    const int DW = MD * D_MODEL;

    char* base = (char*)d_ws;
    size_t off = 0;
    auto alloc = [&](size_t bytes) -> char* {
        char* p = base + off;
        off += (bytes + 255) & ~(size_t)255;
        return p;
    };
    ushortT* Xh    = (ushortT*)alloc((size_t)EW * 2);
    ushortT* Vh    = (ushortT*)alloc((size_t)EW * 2);
    ushortT* TGTh  = (ushortT*)alloc((size_t)DW * 2);
    float*   POSb  = (float*)alloc((size_t)S_TOT * 256 * 4);
    float*   REFEb = (float*)alloc((size_t)S_TOT * 2 * 4);
    float*   REFDb = (float*)alloc((size_t)NQRY * 2 * 4);
    ushortT* Wbf   = (ushortT*)alloc((size_t)5160960 * 2);
    float*   OBIAS = (float*)alloc((size_t)2 * 3 * 288 * 4);
    ushortT* Yh    = (ushortT*)alloc((size_t)ME * 256 * 2);
    char*    R     = alloc((size_t)82252800);
    if (ws_size < off) return;

    ushortT* Qh   = (ushortT*)R;
    float*   OAf  = (float*)(R + 19353600);
    ushortT* OUTh = (ushortT*)(R + 62899200);
    ushortT* HIDh = (ushortT*)R;
    ushortT* QKVh = (ushortT*)R;
    ushortT* SOh  = (ushortT*)(R + 44236800);

    size_t wo = 0;
    auto walloc = [&](size_t elems) -> ushortT* { ushortT* p = Wbf + wo; wo += elems; return p; };
    ushortT* h_enc_offaw = walloc(3 * 288 * 256);
    ushortT* h_enc_vp    = walloc(3 * 65536);
    ushortT* h_enc_op    = walloc(3 * 65536);
    ushortT* h_enc_fc1   = walloc(3 * 262144);
    ushortT* h_enc_fc2   = walloc(3 * 262144);
    ushortT* h_dec_offaw = walloc(3 * 288 * 256);
    ushortT* h_dec_vp    = walloc(3 * 65536);
    ushortT* h_dec_op    = walloc(3 * 65536);
    ushortT* h_dec_fc1   = walloc(3 * 262144);
    ushortT* h_dec_fc2   = walloc(3 * 262144);
    ushortT* h_sa_in     = walloc(3 * 196608);
    ushortT* h_sa_out    = walloc(3 * 65536);
    float* enc_oab = OBIAS;
    float* dec_oab = OBIAS + 3 * 288;

    auto conv = [&](const float* s, ushortT* d, int n) {
        hipLaunchKernelGGL(f2bf_kernel, dim3((n + 255) / 256), dim3(256), 0, stream, s, d, n);
    };
    hipLaunchKernelGGL(conv_offaw_kernel, dim3((3 * 288 * 256 + 255) / 256), dim3(256), 0, stream,
                       enc_off_W, enc_aw_W, h_enc_offaw);
    hipLaunchKernelGGL(conv_offaw_kernel, dim3((3 * 288 * 256 + 255) / 256), dim3(256), 0, stream,
                       dec_off_W, dec_aw_W, h_dec_offaw);
    hipLaunchKernelGGL(conv_offaw_bias_kernel, dim3(4), dim3(256), 0, stream,
                       enc_off_b, enc_aw_b, enc_oab);
    hipLaunchKernelGGL(conv_offaw_bias_kernel, dim3(4), dim3(256), 0, stream,
                       dec_off_b, dec_aw_b, dec_oab);
    conv(enc_vp_W,  h_enc_vp,  3 * 65536);
    conv(enc_op_W,  h_enc_op,  3 * 65536);
    conv(enc_fc1_W, h_enc_fc1, 3 * 262144);
    conv(enc_fc2_W, h_enc_fc2, 3 * 262144);
    conv(dec_vp_W,  h_dec_vp,  3 * 65536);
    conv(dec_op_W,  h_dec_op,  3 * 65536);
    conv(dec_fc1_W, h_dec_fc1, 3 * 262144);
    conv(dec_fc2_W, h_dec_fc2, 3 * 262144);
    conv(sa_in_W,   h_sa_in,   3 * 196608);
    conv(sa_out_W,  h_sa_out,  3 * 65536);

    // ---- setup ----
    hipLaunchKernelGGL(build_pos_kernel, dim3((S_TOT * 256 + 255) / 256), dim3(256), 0, stream,
                       level_embed, POSb);
    hipLaunchKernelGGL(build_ref_kernel, dim3((S_TOT + NQRY + 255) / 256), dim3(256), 0, stream,
                       REFEb, REFDb);
    hipLaunchKernelGGL(transpose_feat_kernel, dim3(113, 8, 8), dim3(256), 0, stream,
                       feat0, Xh, 3600, 0);
    hipLaunchKernelGGL(transpose_feat_kernel, dim3(29, 8, 8), dim3(256), 0, stream,
                       feat1, Xh, 900, 3600);
    hipLaunchKernelGGL(transpose_feat_kernel, dim3(8, 8, 8), dim3(256), 0, stream,
                       feat2, Xh, 225, 4500);
    hipLaunchKernelGGL(build_tgt_kernel, dim3((MD * 64 + 255) / 256), dim3(256), 0, stream,
                       context, query_embed, TGTh);

    // ---- encoder ----
    for (int i = 0; i < 3; i++) {
        gemm_bf16(Xh, h_enc_vp + (size_t)i * 65536, enc_vp_b + i * 256, Vh, ME, 256, 256, 0, 1, stream);
        hipLaunchKernelGGL(add_pos_kernel, dim3((ME * 64 + 255) / 256), dim3(256), 0, stream,
                           Xh, POSb, Qh);
        gemm_bf16(Qh, h_enc_offaw + (size_t)i * 73728, enc_oab + i * 288, OAf, ME, 288, 256, 0, 0, stream);
        hipLaunchKernelGGL(msda_kernel, dim3((ME + MROWS - 1) / MROWS), dim3(256), 0, stream,
                           Vh, OAf, REFEb, OUTh, 0, ME);
        gemm_bf16(OUTh, h_enc_op + (size_t)i * 65536, enc_op_b + i * 256, Yh, ME, 256, 256, 0, 1, stream);
        hipLaunchKernelGGL(ln_res_kernel, dim3((ME + 3) / 4), dim3(256), 0, stream,
                           Xh, Yh, enc_ln1_g + i * 256, enc_ln1_b + i * 256, Xh, (float*)nullptr, ME);
        gemm_bf16(Xh, h_enc_fc1 + (size_t)i * 262144, enc_fc1_b + i * 1024, HIDh, ME, 1024, 256, 1, 1, stream);
        gemm_bf16(HIDh, h_enc_fc2 + (size_t)i * 262144, enc_fc2_b + i * 256, Yh, ME, 256, 1024, 0, 1, stream);
        hipLaunchKernelGGL(ln_res_kernel, dim3((ME + 3) / 4), dim3(256), 0, stream,
                           Xh, Yh, enc_ln2_g + i * 256, enc_ln2_b + i * 256, Xh, (float*)nullptr, ME);
    }

    // ---- decoder ----
    for (int i = 0; i < 3; i++) {
        gemm_bf16(TGTh, h_sa_in + (size_t)i * 196608, sa_in_b + i * 768, QKVh, MD, 768, 256, 0, 1, stream);
        hipLaunchKernelGGL(mha_kernel, dim3((MD * 8 + 255) / 256), dim3(256), 0, stream,
                           QKVh, SOh, MD / 8);
        gemm_bf16(SOh, h_sa_out + (size_t)i * 65536, sa_out_b + i * 256, Yh, MD, 256, 256, 0, 1, stream);
        hipLaunchKernelGGL(ln_res_kernel, dim3((MD + 3) / 4), dim3(256), 0, stream,
                           TGTh, Yh, dec_ln2_g + i * 256, dec_ln2_b + i * 256, TGTh, (float*)nullptr, MD);
        gemm_bf16(Xh, h_dec_vp + (size_t)i * 65536, dec_vp_b + i * 256, Vh, ME, 256, 256, 0, 1, stream);
        gemm_bf16(TGTh, h_dec_offaw + (size_t)i * 73728, dec_oab + i * 288, OAf, MD, 288, 256, 0, 0, stream);
        hipLaunchKernelGGL(msda_kernel, dim3((MD + MROWS - 1) / MROWS), dim3(256), 0, stream,
                           Vh, OAf, REFDb, OUTh, 1, MD);
        gemm_bf16(OUTh, h_dec_op + (size_t)i * 65536, dec_op_b + i * 256, Yh, MD, 256, 256, 0, 1, stream);
        hipLaunchKernelGGL(ln_res_kernel, dim3((MD + 3) / 4), dim3(256), 0, stream,
                           TGTh, Yh, dec_ln1_g + i * 256, dec_ln1_b + i * 256, TGTh, (float*)nullptr, MD);
        gemm_bf16(TGTh, h_dec_fc1 + (size_t)i * 262144, dec_fc1_b + i * 1024, HIDh, MD, 1024, 256, 1, 1, stream);
        gemm_bf16(HIDh, h_dec_fc2 + (size_t)i * 262144, dec_fc2_b + i * 256, Yh, MD, 256, 1024, 0, 1, stream);
        float* outf = (i == 2) ? (float*)d_out : nullptr;
        hipLaunchKernelGGL(ln_res_kernel, dim3((MD + 3) / 4), dim3(256), 0, stream,
                           TGTh, Yh, dec_ln3_g + i * 256, dec_ln3_b + i * 256, TGTh, outf, MD);
    }
}

// Round 9
// 1646.177 us; speedup vs baseline: 1.3809x; 1.3809x over previous
//
#include <hip/hip_runtime.h>
#include <cmath>

#define D_MODEL 256
#define NHEADS 8
#define BSZ 8
#define S_TOT 4725
#define NQRY 3600

typedef unsigned short ushortT;
using bf16x8  = __attribute__((ext_vector_type(8))) __bf16;
using floatx4 = __attribute__((ext_vector_type(4))) float;

__device__ __forceinline__ ushortT f2bf(float f)
{
    union { float f; unsigned u; } v; v.f = f;
    unsigned r = v.u + 0x7FFFu + ((v.u >> 16) & 1u);
    return (ushortT)(r >> 16);
}
__device__ __forceinline__ float bf2f(ushortT u)
{
    union { unsigned u; float f; } v; v.u = ((unsigned)u) << 16;
    return v.f;
}
__device__ __forceinline__ float bits2f(unsigned u)
{
    union { unsigned u; float f; } v; v.u = u;
    return v.f;
}

#define GLD16(gp, lp) __builtin_amdgcn_global_load_lds( \
    (const __attribute__((address_space(1))) void*)(gp), \
    (__attribute__((address_space(3))) void*)(lp), 16, 0, 0)

// ---------------------------------------------------------------------------
// bf16 MFMA GEMM with async global->LDS staging. (unchanged from round 7)
// ---------------------------------------------------------------------------
template<int RELU, int OUTBF>
__global__ __launch_bounds__(256) void gemm_bf16_kernel(
    const ushortT* __restrict__ A, const ushortT* __restrict__ W,
    const float* __restrict__ bias, void* __restrict__ Cout,
    int M, int N, int K)
{
    __shared__ ushortT SM[128 * 32 * 2];
    ushortT* As = SM;
    ushortT* Bs = SM + 128 * 32;
    const int tid  = threadIdx.x;
    const int lane = tid & 63;
    const int wid  = tid >> 6;
    const int bm = blockIdx.x * 128;
    const int bn = blockIdx.y * 128;
    const int wm = (wid & 1) * 64;
    const int wn = (wid >> 1) * 64;
    const int col16 = lane & 15;
    const int quad  = lane >> 4;
    const int srow = lane >> 2;
    const int cperm = (lane & 3) ^ ((lane >> 3) & 3);
    const int rxor = (col16 >> 1) & 3;

    floatx4 acc[4][4];
#pragma unroll
    for (int i = 0; i < 4; i++)
#pragma unroll
        for (int j = 0; j < 4; j++) acc[i][j] = (floatx4){0.f, 0.f, 0.f, 0.f};

    const int rbase = wid * 32;
    for (int k0 = 0; k0 < K; k0 += 32) {
        if (k0) __syncthreads();
#pragma unroll
        for (int j = 0; j < 2; j++) {
            int row = rbase + j * 16 + srow;
            int gm = bm + row; if (gm >= M) gm = M - 1;
            GLD16(A + (size_t)gm * K + k0 + cperm * 8, &As[(rbase + j * 16) * 32]);
            int gn = bn + row; if (gn >= N) gn = N - 1;
            GLD16(W + (size_t)gn * K + k0 + cperm * 8, &Bs[(rbase + j * 16) * 32]);
        }
        __syncthreads();
        bf16x8 av[4], bv[4];
#pragma unroll
        for (int i = 0; i < 4; i++) {
            av[i] = *(const bf16x8*)&As[(wm + i * 16 + col16) * 32 + (quad ^ rxor) * 8];
            bv[i] = *(const bf16x8*)&Bs[(wn + i * 16 + col16) * 32 + (quad ^ rxor) * 8];
        }
#pragma unroll
        for (int mi = 0; mi < 4; mi++)
#pragma unroll
            for (int ni = 0; ni < 4; ni++)
                acc[mi][ni] = __builtin_amdgcn_mfma_f32_16x16x32_bf16(
                    av[mi], bv[ni], acc[mi][ni], 0, 0, 0);
    }

    if (OUTBF) {
        __syncthreads();
        ushortT* cs = SM + wid * (16 * 72);
        const int row_l = lane >> 2;
        const int colg  = (lane & 3) * 16;
#pragma unroll
        for (int mi = 0; mi < 4; mi++) {
#pragma unroll
            for (int ni = 0; ni < 4; ni++) {
                int gn = bn + wn + ni * 16 + col16;
                float bs = bias[gn < N ? gn : N - 1];
#pragma unroll
                for (int r = 0; r < 4; r++) {
                    float v = acc[mi][ni][r] + bs;
                    if (RELU) v = fmaxf(v, 0.f);
                    cs[(quad * 4 + r) * 72 + ni * 16 + col16] = f2bf(v);
                }
            }
            int gm = bm + wm + mi * 16 + row_l;
            int gn0 = bn + wn + colg;
            if (gm < M) {
                ushortT* dst = (ushortT*)Cout + (size_t)gm * N + gn0;
                if (gn0 + 8 <= N)  *(uint4*)dst       = *(uint4*)&cs[row_l * 72 + colg];
                if (gn0 + 16 <= N) *(uint4*)(dst + 8) = *(uint4*)&cs[row_l * 72 + colg + 8];
            }
        }
    } else {
#pragma unroll
        for (int ni = 0; ni < 4; ni++) {
            int gn = bn + wn + ni * 16 + col16;
            if (gn >= N) continue;
            float bs = bias[gn];
#pragma unroll
            for (int mi = 0; mi < 4; mi++) {
#pragma unroll
                for (int r = 0; r < 4; r++) {
                    int gm = bm + wm + mi * 16 + quad * 4 + r;
                    if (gm >= M) continue;
                    float v = acc[mi][ni][r] + bs;
                    if (RELU) v = fmaxf(v, 0.f);
                    ((float*)Cout)[(size_t)gm * N + gn] = v;
                }
            }
        }
    }
}

static inline void gemm_bf16(const ushortT* A, const ushortT* W, const float* bias,
                             void* C, int M, int N, int K, int relu, int outbf,
                             hipStream_t s)
{
    dim3 g((M + 127) / 128, (N + 127) / 128);
    if (relu) {
        if (outbf) hipLaunchKernelGGL((gemm_bf16_kernel<1,1>), g, dim3(256), 0, s, A, W, bias, C, M, N, K);
        else       hipLaunchKernelGGL((gemm_bf16_kernel<1,0>), g, dim3(256), 0, s, A, W, bias, C, M, N, K);
    } else {
        if (outbf) hipLaunchKernelGGL((gemm_bf16_kernel<0,1>), g, dim3(256), 0, s, A, W, bias, C, M, N, K);
        else       hipLaunchKernelGGL((gemm_bf16_kernel<0,0>), g, dim3(256), 0, s, A, W, bias, C, M, N, K);
    }
}

// ---------------------------------------------------------------------------
__global__ void f2bf_kernel(const float* __restrict__ src, ushortT* __restrict__ dst, int n)
{
    int t = blockIdx.x * blockDim.x + threadIdx.x;
    if (t < n) dst[t] = f2bf(src[t]);
}

__global__ void conv_offaw_kernel(const float* __restrict__ offW, const float* __restrict__ awW,
                                  ushortT* __restrict__ dst)
{
    int t = blockIdx.x * blockDim.x + threadIdx.x;
    if (t >= 3 * 288 * 256) return;
    int c = t & 255;
    int r = (t >> 8) % 288;
    int i = t / (288 * 256);
    float v = (r < 192) ? offW[((size_t)i * 192 + r) * 256 + c]
                        : awW[((size_t)i * 96 + (r - 192)) * 256 + c];
    dst[t] = f2bf(v);
}

__global__ void conv_offaw_bias_kernel(const float* __restrict__ offb, const float* __restrict__ awb,
                                       float* __restrict__ dst)
{
    int t = blockIdx.x * blockDim.x + threadIdx.x;
    if (t >= 3 * 288) return;
    int r = t % 288;
    int i = t / 288;
    dst[t] = (r < 192) ? offb[i * 192 + r] : awb[i * 96 + (r - 192)];
}

__device__ __forceinline__ void level_of(int s, int& l, int& H, int& W, int& hw)
{
    if (s < 3600)      { l = 0; H = 60; W = 60; hw = s; }
    else if (s < 4500) { l = 1; H = 30; W = 30; hw = s - 3600; }
    else               { l = 2; H = 15; W = 15; hw = s - 4500; }
}

__global__ __launch_bounds__(256) void transpose_feat_kernel(
    const float* __restrict__ f, ushortT* __restrict__ Xh, int HW, int s0)
{
    __shared__ float tile[32][33];
    const int b  = blockIdx.z;
    const int hw0 = blockIdx.x * 32;
    const int d0  = blockIdx.y * 32;
    const int tx = threadIdx.x & 31;
    const int ty = threadIdx.x >> 5;
    const float* fb = f + ((size_t)b * 256 + d0) * HW + hw0;
#pragma unroll
    for (int r = ty; r < 32; r += 8) {
        if (hw0 + tx < HW) tile[r][tx] = fb[(size_t)r * HW + tx];
    }
    __syncthreads();
    ushortT* xb = Xh + ((size_t)b * S_TOT + s0 + hw0) * 256 + d0;
#pragma unroll
    for (int r = ty; r < 32; r += 8) {
        if (hw0 + r < HW) xb[(size_t)r * 256 + tx] = f2bf(tile[tx][r]);
    }
}

__global__ void build_pos_kernel(const float* __restrict__ level_embed, float* __restrict__ pos)
{
    int t = blockIdx.x * blockDim.x + threadIdx.x;
    if (t >= S_TOT * D_MODEL) return;
    int d = t & 255;
    int s = t >> 8;
    int l, H, W, hw; level_of(s, l, H, W, hw);
    int y = hw / W, x = hw % W;
    int dd = (d < 128) ? d : d - 128;
    float v = (d < 128)
        ? ((float)(y + 1)) / ((float)H + 1e-6f) * 6.28318530717958647692f
        : ((float)(x + 1)) / ((float)W + 1e-6f) * 6.28318530717958647692f;
    float tpow = powf(10000.f, (float)(2 * (dd >> 1)) * (1.f / 128.f));
    float arg = v / tpow;
    float val = (dd & 1) ? cosf(arg) : sinf(arg);
    pos[t] = val + level_embed[l * D_MODEL + d];
}

__global__ void build_ref_kernel(float* __restrict__ refE, float* __restrict__ refD)
{
    int t = blockIdx.x * blockDim.x + threadIdx.x;
    if (t < S_TOT) {
        int l, H, W, hw; level_of(t, l, H, W, hw);
        int y = hw / W, x = hw % W;
        refE[2 * t]     = ((float)x + 0.5f) / (float)W;
        refE[2 * t + 1] = ((float)y + 0.5f) / (float)H;
    } else if (t < S_TOT + NQRY) {
        int q = t - S_TOT;
        int y = q / 60, x = q % 60;
        refD[2 * q]     = ((float)x + 0.5f) / 60.f;
        refD[2 * q + 1] = ((float)y + 0.5f) / 60.f;
    }
}

__global__ void build_tgt_kernel(const float* __restrict__ context, const float* __restrict__ qe,
                                 ushortT* __restrict__ TGTh)
{
    int t = blockIdx.x * blockDim.x + threadIdx.x;
    if (t >= NQRY * BSZ * 64) return;
    int gi = t & 63;
    int row = t >> 6;
    int nq = row >> 3;
    int d0 = gi * 4;
    const float4 c4 = *(const float4*)(context + (size_t)row * 256 + d0);
    const float4 q4 = *(const float4*)(qe + (size_t)nq * 256 + d0);
    ushortT pk[4] = { f2bf(c4.x + q4.x), f2bf(c4.y + q4.y), f2bf(c4.z + q4.z), f2bf(c4.w + q4.w) };
    *(uint2*)(TGTh + (size_t)row * 256 + d0) = *(uint2*)pk;
}

__global__ void add_pos_kernel(const ushortT* __restrict__ Xh, const float* __restrict__ pos,
                               ushortT* __restrict__ Qh)
{
    int t = blockIdx.x * blockDim.x + threadIdx.x;
    if (t >= BSZ * S_TOT * 64) return;
    int gi = t & 63;
    int row = t >> 6;
    int s = row % S_TOT;
    int d0 = gi * 4;
    ushortT x4[4];
    *(uint2*)x4 = *(const uint2*)(Xh + (size_t)row * 256 + d0);
    const float4 p4 = *(const float4*)(pos + (size_t)s * 256 + d0);
    ushortT pk[4] = { f2bf(bf2f(x4[0]) + p4.x), f2bf(bf2f(x4[1]) + p4.y),
                      f2bf(bf2f(x4[2]) + p4.z), f2bf(bf2f(x4[3]) + p4.w) };
    *(uint2*)(Qh + (size_t)row * 256 + d0) = *(uint2*)pk;
}

// ---------------------------------------------------------------------------
// MSDA sampling. Branchless per-tap 4-corner gather (4 loads batched in
// flight), but tap loop NOT unrolled (#pragma unroll 1) to cap register
// pressure — round 8 showed full unroll costs 244 VGPR -> 11% occupancy.
// Level loop stays unrolled so H/W/s0 fold to constants.
// ---------------------------------------------------------------------------
#define MROWS 8
__global__ __launch_bounds__(256) void msda_kernel(
    const ushortT* __restrict__ value, const float* __restrict__ oa,
    const float* __restrict__ ref, ushortT* __restrict__ out,
    int mode, int total_rows)
{
    __shared__ float sOff[MROWS][192];
    __shared__ float sW[MROWS][96];
    const int br0 = blockIdx.x * MROWS;

    for (int idx = threadIdx.x; idx < MROWS * 288; idx += 256) {
        int r = idx / 288, c = idx - r * 288;
        int lm = br0 + r;
        float v = (lm < total_rows) ? oa[(size_t)lm * 288 + c] : 0.f;
        if (c < 192) sOff[r][c] = v;
        else         sW[r][c - 192] = v;
    }
    __syncthreads();
    if (threadIdx.x < 64) {
        int r = threadIdx.x >> 3, h = threadIdx.x & 7;
        float* p = &sW[r][h * 12];
        float mx = p[0];
#pragma unroll
        for (int i = 1; i < 12; i++) mx = fmaxf(mx, p[i]);
        float ssum = 0.f;
        float e[12];
#pragma unroll
        for (int i = 0; i < 12; i++) { e[i] = expf(p[i] - mx); ssum += e[i]; }
        float inv = 1.f / ssum;
#pragma unroll
        for (int i = 0; i < 12; i++) p[i] = e[i] * inv;
    }
    __syncthreads();

    const int r  = threadIdx.x >> 5;
    const int h  = (threadIdx.x >> 2) & 7;
    const int cg = threadIdx.x & 3;
    const int lm = br0 + r;
    if (lm >= total_rows) return;
    int b, q;
    if (mode == 0) { b = lm / S_TOT; q = lm - b * S_TOT; }
    else           { q = lm >> 3;    b = lm & 7; }
    const float rx = ref[2 * q], ry = ref[2 * q + 1];
    const float* offp = &sOff[r][h * 24];
    const float* wp   = &sW[r][h * 12];

    float acc[8] = {};
    const int HWs[3][3] = {{60, 60, 0}, {30, 30, 3600}, {15, 15, 4500}};
#pragma unroll
    for (int l = 0; l < 3; l++) {
        const int H = HWs[l][0], W = HWs[l][1], s0 = HWs[l][2];
        const ushortT* vbase = value + ((size_t)b * S_TOT + s0) * 256 + h * 32 + cg * 8;
        const float fW = (float)W, fH = (float)H;
#pragma unroll 1
        for (int p = 0; p < 4; p++) {
            float ox = offp[(l * 4 + p) * 2];
            float oy = offp[(l * 4 + p) * 2 + 1];
            float w  = wp[l * 4 + p];
            float lx = rx * fW + ox - 0.5f;
            float ly = ry * fH + oy - 0.5f;
            float x0f = floorf(lx), y0f = floorf(ly);
            int x0 = (int)x0f, y0 = (int)y0f;
            float wx1 = lx - x0f, wy1 = ly - y0f;
            float mx0 = ((unsigned)x0       < (unsigned)W) ? (1.f - wx1) : 0.f;
            float mx1 = ((unsigned)(x0 + 1) < (unsigned)W) ? wx1         : 0.f;
            float my0 = ((unsigned)y0       < (unsigned)H) ? (1.f - wy1) : 0.f;
            float my1 = ((unsigned)(y0 + 1) < (unsigned)H) ? wy1         : 0.f;
            int xc0 = min(max(x0, 0), W - 1);
            int xc1 = min(max(x0 + 1, 0), W - 1);
            int yc0 = min(max(y0, 0), H - 1);
            int yc1 = min(max(y0 + 1, 0), H - 1);
            const uint4 v00 = *(const uint4*)(vbase + (size_t)(yc0 * W + xc0) * 256);
            const uint4 v01 = *(const uint4*)(vbase + (size_t)(yc0 * W + xc1) * 256);
            const uint4 v10 = *(const uint4*)(vbase + (size_t)(yc1 * W + xc0) * 256);
            const uint4 v11 = *(const uint4*)(vbase + (size_t)(yc1 * W + xc1) * 256);
            float w00 = w * my0 * mx0, w01 = w * my0 * mx1;
            float w10 = w * my1 * mx0, w11 = w * my1 * mx1;
#define ACC4(i, lo00, lo01, lo10, lo11) \
            acc[i] = fmaf(w00, bits2f(lo00), acc[i]); \
            acc[i] = fmaf(w01, bits2f(lo01), acc[i]); \
            acc[i] = fmaf(w10, bits2f(lo10), acc[i]); \
            acc[i] = fmaf(w11, bits2f(lo11), acc[i]);
            ACC4(0, v00.x << 16, v01.x << 16, v10.x << 16, v11.x << 16)
            ACC4(1, v00.x & 0xFFFF0000u, v01.x & 0xFFFF0000u, v10.x & 0xFFFF0000u, v11.x & 0xFFFF0000u)
            ACC4(2, v00.y << 16, v01.y << 16, v10.y << 16, v11.y << 16)
            ACC4(3, v00.y & 0xFFFF0000u, v01.y & 0xFFFF0000u, v10.y & 0xFFFF0000u, v11.y & 0xFFFF0000u)
            ACC4(4, v00.z << 16, v01.z << 16, v10.z << 16, v11.z << 16)
            ACC4(5, v00.z & 0xFFFF0000u, v01.z & 0xFFFF0000u, v10.z & 0xFFFF0000u, v11.z & 0xFFFF0000u)
            ACC4(6, v00.w << 16, v01.w << 16, v10.w << 16, v11.w << 16)
            ACC4(7, v00.w & 0xFFFF0000u, v01.w & 0xFFFF0000u, v10.w & 0xFFFF0000u, v11.w & 0xFFFF0000u)
#undef ACC4
        }
    }
    ushortT pk[8];
#pragma unroll
    for (int i = 0; i < 8; i++) pk[i] = f2bf(acc[i]);
    *(uint4*)(out + (size_t)lm * 256 + h * 32 + cg * 8) = *(uint4*)pk;
}

// ---------------------------------------------------------------------------
// LN over bf16 residual stream
// ---------------------------------------------------------------------------
__global__ void ln_res_kernel(const ushortT* __restrict__ x, const ushortT* __restrict__ a,
                              const float* __restrict__ g, const float* __restrict__ b,
                              ushortT* __restrict__ outh, float* __restrict__ outf, int M)
{
    int wave = threadIdx.x >> 6;
    int lane = threadIdx.x & 63;
    int row = blockIdx.x * 4 + wave;
    if (row >= M) return;
    const int d0 = lane * 4;
    ushortT x4[4], a4[4];
    *(uint2*)x4 = *(const uint2*)(x + (size_t)row * 256 + d0);
    *(uint2*)a4 = *(const uint2*)(a + (size_t)row * 256 + d0);
    float v[4];
    float s = 0.f;
#pragma unroll
    for (int i = 0; i < 4; i++) { v[i] = bf2f(x4[i]) + bf2f(a4[i]); s += v[i]; }
#pragma unroll
    for (int o = 32; o > 0; o >>= 1) s += __shfl_down(s, o);
    s = __shfl(s, 0);
    float mean = s * (1.f / 256.f);
    float vs = 0.f;
#pragma unroll
    for (int i = 0; i < 4; i++) { float d = v[i] - mean; vs += d * d; }
#pragma unroll
    for (int o = 32; o > 0; o >>= 1) vs += __shfl_down(vs, o);
    vs = __shfl(vs, 0);
    float inv = rsqrtf(vs * (1.f / 256.f) + 1e-5f);
    const float4 g4 = *(const float4*)(g + d0);
    const float4 b4 = *(const float4*)(b + d0);
    float o0 = (v[0] - mean) * inv * g4.x + b4.x;
    float o1 = (v[1] - mean) * inv * g4.y + b4.y;
    float o2 = (v[2] - mean) * inv * g4.z + b4.z;
    float o3 = (v[3] - mean) * inv * g4.w + b4.w;
    ushortT pk[4] = { f2bf(o0), f2bf(o1), f2bf(o2), f2bf(o3) };
    *(uint2*)(outh + (size_t)row * 256 + d0) = *(uint2*)pk;
    if (outf) {
        float4 of = { o0, o1, o2, o3 };
        *(float4*)(outf + (size_t)row * 256 + d0) = of;
    }
}

// Decoder self-attn over L=8 (batch). qkv bf16 rows n*8+l; out bf16.
__global__ void mha_kernel(const ushortT* __restrict__ qkv, ushortT* __restrict__ o, int nCnt)
{
    int t = blockIdx.x * blockDim.x + threadIdx.x;
    if (t >= nCnt * 64) return;
    int l = t & 7;
    int h = (t >> 3) & 7;
    int n = t >> 6;
    const ushortT* qp = qkv + (size_t)(n * 8 + l) * 768 + h * 32;
    float q[32];
#pragma unroll
    for (int d = 0; d < 32; d++) q[d] = bf2f(qp[d]);
    float sc[8];
#pragma unroll
    for (int s = 0; s < 8; s++) {
        const ushortT* kp = qkv + (size_t)(n * 8 + s) * 768 + 256 + h * 32;
        float acc = 0.f;
#pragma unroll
        for (int d = 0; d < 32; d++) acc = fmaf(q[d], bf2f(kp[d]), acc);
        sc[s] = acc * 0.17677669529663688f;
    }
    float mx = sc[0];
#pragma unroll
    for (int s = 1; s < 8; s++) mx = fmaxf(mx, sc[s]);
    float sum = 0.f;
#pragma unroll
    for (int s = 0; s < 8; s++) { sc[s] = expf(sc[s] - mx); sum += sc[s]; }
    float inv = 1.f / sum;
    float outv[32] = {};
#pragma unroll
    for (int s = 0; s < 8; s++) {
        const ushortT* vp = qkv + (size_t)(n * 8 + s) * 768 + 512 + h * 32;
        float a = sc[s] * inv;
#pragma unroll
        for (int d = 0; d < 32; d++) outv[d] = fmaf(a, bf2f(vp[d]), outv[d]);
    }
    ushortT* op = o + (size_t)(n * 8 + l) * 256 + h * 32;
#pragma unroll
    for (int d = 0; d < 32; d++) op[d] = f2bf(outv[d]);
}

// ---------------------------------------------------------------------------
extern "C" void kernel_launch(void* const* d_in, const int* in_sizes, int n_in,
                              void* d_out, int out_size, void* d_ws, size_t ws_size,
                              hipStream_t stream)
{
    const float* feat0       = (const float*)d_in[0];
    const float* feat1       = (const float*)d_in[1];
    const float* feat2       = (const float*)d_in[2];
    const float* context     = (const float*)d_in[3];
    const float* query_embed = (const float*)d_in[4];
    const float* level_embed = (const float*)d_in[5];
    const float* enc_off_W = (const float*)d_in[6];
    const float* enc_off_b = (const float*)d_in[7];
    const float* enc_aw_W  = (const float*)d_in[8];
    const float* enc_aw_b  = (const float*)d_in[9];
    const float* enc_vp_W  = (const float*)d_in[10];
    const float* enc_vp_b  = (const float*)d_in[11];
    const float* enc_op_W  = (const float*)d_in[12];
    const float* enc_op_b  = (const float*)d_in[13];
    const float* enc_fc1_W = (const float*)d_in[14];
    const float* enc_fc1_b = (const float*)d_in[15];
    const float* enc_fc2_W = (const float*)d_in[16];
    const float* enc_fc2_b = (const float*)d_in[17];
    const float* enc_ln1_g = (const float*)d_in[18];
    const float* enc_ln1_b = (const float*)d_in[19];
    const float* enc_ln2_g = (const float*)d_in[20];
    const float* enc_ln2_b = (const float*)d_in[21];
    const float* dec_off_W = (const float*)d_in[22];
    const float* dec_off_b = (const float*)d_in[23];
    const float* dec_aw_W  = (const float*)d_in[24];
    const float* dec_aw_b  = (const float*)d_in[25];
    const float* dec_vp_W  = (const float*)d_in[26];
    const float* dec_vp_b  = (const float*)d_in[27];
    const float* dec_op_W  = (const float*)d_in[28];
    const float* dec_op_b  = (const float*)d_in[29];
    const float* dec_fc1_W = (const float*)d_in[30];
    const float* dec_fc1_b = (const float*)d_in[31];
    const float* dec_fc2_W = (const float*)d_in[32];
    const float* dec_fc2_b = (const float*)d_in[33];
    const float* dec_ln1_g = (const float*)d_in[34];
    const float* dec_ln1_b = (const float*)d_in[35];
    const float* dec_ln2_g = (const float*)d_in[36];
    const float* dec_ln2_b = (const float*)d_in[37];
    const float* sa_in_W   = (const float*)d_in[38];
    const float* sa_in_b   = (const float*)d_in[39];
    const float* sa_out_W  = (const float*)d_in[40];
    const float* sa_out_b  = (const float*)d_in[41];
    const float* dec_ln3_g = (const float*)d_in[42];
    const float* dec_ln3_b = (const float*)d_in[43];

    const int ME = BSZ * S_TOT;       // 37800
    const int MD = BSZ * NQRY;        // 28800
    const int EW = ME * D_MODEL;
    const int DW = MD * D_MODEL;

    char* base = (char*)d_ws;
    size_t off = 0;
    auto alloc = [&](size_t bytes) -> char* {
        char* p = base + off;
        off += (bytes + 255) & ~(size_t)255;
        return p;
    };
    ushortT* Xh    = (ushortT*)alloc((size_t)EW * 2);
    ushortT* Vh    = (ushortT*)alloc((size_t)EW * 2);
    ushortT* TGTh  = (ushortT*)alloc((size_t)DW * 2);
    float*   POSb  = (float*)alloc((size_t)S_TOT * 256 * 4);
    float*   REFEb = (float*)alloc((size_t)S_TOT * 2 * 4);
    float*   REFDb = (float*)alloc((size_t)NQRY * 2 * 4);
    ushortT* Wbf   = (ushortT*)alloc((size_t)5160960 * 2);
    float*   OBIAS = (float*)alloc((size_t)2 * 3 * 288 * 4);
    ushortT* Yh    = (ushortT*)alloc((size_t)ME * 256 * 2);
    char*    R     = alloc((size_t)82252800);
    if (ws_size < off) return;

    ushortT* Qh   = (ushortT*)R;
    float*   OAf  = (float*)(R + 19353600);
    ushortT* OUTh = (ushortT*)(R + 62899200);
    ushortT* HIDh = (ushortT*)R;
    ushortT* QKVh = (ushortT*)R;
    ushortT* SOh  = (ushortT*)(R + 44236800);

    size_t wo = 0;
    auto walloc = [&](size_t elems) -> ushortT* { ushortT* p = Wbf + wo; wo += elems; return p; };
    ushortT* h_enc_offaw = walloc(3 * 288 * 256);
    ushortT* h_enc_vp    = walloc(3 * 65536);
    ushortT* h_enc_op    = walloc(3 * 65536);
    ushortT* h_enc_fc1   = walloc(3 * 262144);
    ushortT* h_enc_fc2   = walloc(3 * 262144);
    ushortT* h_dec_offaw = walloc(3 * 288 * 256);
    ushortT* h_dec_vp    = walloc(3 * 65536);
    ushortT* h_dec_op    = walloc(3 * 65536);
    ushortT* h_dec_fc1   = walloc(3 * 262144);
    ushortT* h_dec_fc2   = walloc(3 * 262144);
    ushortT* h_sa_in     = walloc(3 * 196608);
    ushortT* h_sa_out    = walloc(3 * 65536);
    float* enc_oab = OBIAS;
    float* dec_oab = OBIAS + 3 * 288;

    auto conv = [&](const float* s, ushortT* d, int n) {
        hipLaunchKernelGGL(f2bf_kernel, dim3((n + 255) / 256), dim3(256), 0, stream, s, d, n);
    };
    hipLaunchKernelGGL(conv_offaw_kernel, dim3((3 * 288 * 256 + 255) / 256), dim3(256), 0, stream,
                       enc_off_W, enc_aw_W, h_enc_offaw);
    hipLaunchKernelGGL(conv_offaw_kernel, dim3((3 * 288 * 256 + 255) / 256), dim3(256), 0, stream,
                       dec_off_W, dec_aw_W, h_dec_offaw);
    hipLaunchKernelGGL(conv_offaw_bias_kernel, dim3(4), dim3(256), 0, stream,
                       enc_off_b, enc_aw_b, enc_oab);
    hipLaunchKernelGGL(conv_offaw_bias_kernel, dim3(4), dim3(256), 0, stream,
                       dec_off_b, dec_aw_b, dec_oab);
    conv(enc_vp_W,  h_enc_vp,  3 * 65536);
    conv(enc_op_W,  h_enc_op,  3 * 65536);
    conv(enc_fc1_W, h_enc_fc1, 3 * 262144);
    conv(enc_fc2_W, h_enc_fc2, 3 * 262144);
    conv(dec_vp_W,  h_dec_vp,  3 * 65536);
    conv(dec_op_W,  h_dec_op,  3 * 65536);
    conv(dec_fc1_W, h_dec_fc1, 3 * 262144);
    conv(dec_fc2_W, h_dec_fc2, 3 * 262144);
    conv(sa_in_W,   h_sa_in,   3 * 196608);
    conv(sa_out_W,  h_sa_out,  3 * 65536);

    // ---- setup ----
    hipLaunchKernelGGL(build_pos_kernel, dim3((S_TOT * 256 + 255) / 256), dim3(256), 0, stream,
                       level_embed, POSb);
    hipLaunchKernelGGL(build_ref_kernel, dim3((S_TOT + NQRY + 255) / 256), dim3(256), 0, stream,
                       REFEb, REFDb);
    hipLaunchKernelGGL(transpose_feat_kernel, dim3(113, 8, 8), dim3(256), 0, stream,
                       feat0, Xh, 3600, 0);
    hipLaunchKernelGGL(transpose_feat_kernel, dim3(29, 8, 8), dim3(256), 0, stream,
                       feat1, Xh, 900, 3600);
    hipLaunchKernelGGL(transpose_feat_kernel, dim3(8, 8, 8), dim3(256), 0, stream,
                       feat2, Xh, 225, 4500);
    hipLaunchKernelGGL(build_tgt_kernel, dim3((MD * 64 + 255) / 256), dim3(256), 0, stream,
                       context, query_embed, TGTh);

    // ---- encoder ----
    for (int i = 0; i < 3; i++) {
        gemm_bf16(Xh, h_enc_vp + (size_t)i * 65536, enc_vp_b + i * 256, Vh, ME, 256, 256, 0, 1, stream);
        hipLaunchKernelGGL(add_pos_kernel, dim3((ME * 64 + 255) / 256), dim3(256), 0, stream,
                           Xh, POSb, Qh);
        gemm_bf16(Qh, h_enc_offaw + (size_t)i * 73728, enc_oab + i * 288, OAf, ME, 288, 256, 0, 0, stream);
        hipLaunchKernelGGL(msda_kernel, dim3((ME + MROWS - 1) / MROWS), dim3(256), 0, stream,
                           Vh, OAf, REFEb, OUTh, 0, ME);
        gemm_bf16(OUTh, h_enc_op + (size_t)i * 65536, enc_op_b + i * 256, Yh, ME, 256, 256, 0, 1, stream);
        hipLaunchKernelGGL(ln_res_kernel, dim3((ME + 3) / 4), dim3(256), 0, stream,
                           Xh, Yh, enc_ln1_g + i * 256, enc_ln1_b + i * 256, Xh, (float*)nullptr, ME);
        gemm_bf16(Xh, h_enc_fc1 + (size_t)i * 262144, enc_fc1_b + i * 1024, HIDh, ME, 1024, 256, 1, 1, stream);
        gemm_bf16(HIDh, h_enc_fc2 + (size_t)i * 262144, enc_fc2_b + i * 256, Yh, ME, 256, 1024, 0, 1, stream);
        hipLaunchKernelGGL(ln_res_kernel, dim3((ME + 3) / 4), dim3(256), 0, stream,
                           Xh, Yh, enc_ln2_g + i * 256, enc_ln2_b + i * 256, Xh, (float*)nullptr, ME);
    }

    // ---- decoder ----
    for (int i = 0; i < 3; i++) {
        gemm_bf16(TGTh, h_sa_in + (size_t)i * 196608, sa_in_b + i * 768, QKVh, MD, 768, 256, 0, 1, stream);
        hipLaunchKernelGGL(mha_kernel, dim3((MD * 8 + 255) / 256), dim3(256), 0, stream,
                           QKVh, SOh, MD / 8);
        gemm_bf16(SOh, h_sa_out + (size_t)i * 65536, sa_out_b + i * 256, Yh, MD, 256, 256, 0, 1, stream);
        hipLaunchKernelGGL(ln_res_kernel, dim3((MD + 3) / 4), dim3(256), 0, stream,
                           TGTh, Yh, dec_ln2_g + i * 256, dec_ln2_b + i * 256, TGTh, (float*)nullptr, MD);
        gemm_bf16(Xh, h_dec_vp + (size_t)i * 65536, dec_vp_b + i * 256, Vh, ME, 256, 256, 0, 1, stream);
        gemm_bf16(TGTh, h_dec_offaw + (size_t)i * 73728, dec_oab + i * 288, OAf, MD, 288, 256, 0, 0, stream);
        hipLaunchKernelGGL(msda_kernel, dim3((MD + MROWS - 1) / MROWS), dim3(256), 0, stream,
                           Vh, OAf, REFDb, OUTh, 1, MD);
        gemm_bf16(OUTh, h_dec_op + (size_t)i * 65536, dec_op_b + i * 256, Yh, MD, 256, 256, 0, 1, stream);
        hipLaunchKernelGGL(ln_res_kernel, dim3((MD + 3) / 4), dim3(256), 0, stream,
                           TGTh, Yh, dec_ln1_g + i * 256, dec_ln1_b + i * 256, TGTh, (float*)nullptr, MD);
        gemm_bf16(TGTh, h_dec_fc1 + (size_t)i * 262144, dec_fc1_b + i * 1024, HIDh, MD, 1024, 256, 1, 1, stream);
        gemm_bf16(HIDh, h_dec_fc2 + (size_t)i * 262144, dec_fc2_b + i * 256, Yh, MD, 256, 1024, 0, 1, stream);
        float* outf = (i == 2) ? (float*)d_out : nullptr;
        hipLaunchKernelGGL(ln_res_kernel, dim3((MD + 3) / 4), dim3(256), 0, stream,
                           TGTh, Yh, dec_ln3_g + i * 256, dec_ln3_b + i * 256, TGTh, outf, MD);
    }
}